// Round 12
// baseline (17053.267 us; speedup 1.0000x reference)
//
#include <hip/hip_runtime.h>
#include <hip/hip_bf16.h>

#define Bq 64
#define Tq 512
#define Eq 128
#define Hq 256
#define NTAGS 50
#define Mq (Bq*Tq)   // 32768

__device__ __forceinline__ float sigmoidf_(float x) { return 1.f / (1.f + __expf(-x)); }
__device__ __forceinline__ float tanhf_(float x) {
    float e = __expf(2.f * x);
    return 1.f - 2.f / (e + 1.f);
}

// ---------------- dtype detection: int32 vs int64 for words/lengths ----------------
__global__ void detect_int64(const unsigned* __restrict__ words,
                             const unsigned* __restrict__ lens,
                             unsigned* __restrict__ dflags) {
    __shared__ int wbad, lbad, wnz, lnz;
    if (threadIdx.x == 0) { wbad = 0; lbad = 0; wnz = 0; lnz = 0; }
    __syncthreads();
    for (int i = threadIdx.x; i < 16384; i += blockDim.x) {
        if (words[2 * i + 1] != 0u) wbad = 1;
        if (words[2 * i] != 0u) wnz = 1;
    }
    for (int i = threadIdx.x; i < 32; i += blockDim.x) {
        if (lens[2 * i + 1] != 0u) lbad = 1;
        if (lens[2 * i] != 0u) lnz = 1;
    }
    __syncthreads();
    if (threadIdx.x == 0) {
        unsigned f = 0;
        if (!wbad && wnz) f |= 1u;
        if (!lbad && lnz) f |= 2u;
        dflags[0] = f;
    }
}

// ---------------- bias: bias[l][d][n] = bih + bhh ----------------
__global__ void bias_kernel(const float* b1f_ih, const float* b1f_hh,
                            const float* b1b_ih, const float* b1b_hh,
                            const float* b2f_ih, const float* b2f_hh,
                            const float* b2b_ih, const float* b2b_hh,
                            float* bias) {   // [4][1024]: l1f,l1b,l2f,l2b
    int i = blockIdx.x * blockDim.x + threadIdx.x;
    if (i >= 4096) return;
    int l = i >> 11, d = (i >> 10) & 1, nn = i & 1023;
    float v;
    if (l == 0) v = d ? (b1b_ih[nn] + b1b_hh[nn]) : (b1f_ih[nn] + b1f_hh[nn]);
    else        v = d ? (b2b_ih[nn] + b2b_hh[nn]) : (b2f_ih[nn] + b2f_hh[nn]);
    bias[i] = v;
}

// ---------------- Whh packing: W[1024][256] -> P[((k4)*256+j)*16 + g*4 + kk] ----------------
// k = k4*4 + kk (k4 = 0..63). Lane j's 64B chunk holds the four float4s (g=0..3).
__global__ void pack_whh(const float* __restrict__ W, float* __restrict__ P) {
    int t = blockIdx.x * 256 + threadIdx.x;   // 0..65535
    if (t >= 65536) return;
    int g = t & 3, j = (t >> 2) & 255, k4 = t >> 10;   // k4: 0..63
    int row = g * 256 + j;
    float4 v = *(const float4*)(W + (size_t)row * 256 + k4 * 4);
    ((float4*)P)[t] = v;
}

// ---------------- f32 GEMM: C[M,N] = A[M,K] @ W[N,K]^T + bias (unchanged, passing) ----------------
// AMODE: 0 = A f32, 2 = A gathered from emb via words (dtype-adaptive), 3 = A f16
// OUTT:  0 = f32, 1 = f16
template<int AMODE, int OUTT>
__global__ __launch_bounds__(256)
void gemm_kernel(const void* __restrict__ Aptr, const unsigned* __restrict__ words_u32,
                 const float* __restrict__ emb, const unsigned* __restrict__ dflags,
                 const float* __restrict__ Wlo, const float* __restrict__ Whi,
                 const float* __restrict__ blo, const float* __restrict__ bhi,
                 void* __restrict__ Cptr, int M, int N, int K)
{
    __shared__ float As[16][68];
    __shared__ float Ws[16][68];
    const int tx = threadIdx.x & 15, ty = threadIdx.x >> 4;
    const int m0 = blockIdx.y * 64, n0 = blockIdx.x * 64;
    const bool hi = ((m0 & 511) >= 256);
    const float* W = hi ? Whi : Wlo;
    const float* bias = hi ? bhi : blo;
    const int lr = threadIdx.x >> 2, lc = threadIdx.x & 3;
    bool w64 = false;
    if (AMODE == 2) w64 = (dflags[0] & 1u) != 0u;
    float acc[4][4] = {};
    for (int k0 = 0; k0 < K; k0 += 16) {
        float a4[4], w4[4];
        if (AMODE == 2) {
            int m = m0 + lr;
            int w = (int)(w64 ? words_u32[2 * m] : words_u32[m]);
            float4 v = *(const float4*)(emb + (size_t)w * Eq + k0 + lc * 4);
            a4[0] = v.x; a4[1] = v.y; a4[2] = v.z; a4[3] = v.w;
        } else if (AMODE == 0) {
            float4 v = *(const float4*)((const float*)Aptr + (size_t)(m0 + lr) * K + k0 + lc * 4);
            a4[0] = v.x; a4[1] = v.y; a4[2] = v.z; a4[3] = v.w;
        } else {
            const _Float16* Ab = (const _Float16*)Aptr + (size_t)(m0 + lr) * K + k0 + lc * 4;
            #pragma unroll
            for (int q = 0; q < 4; ++q) a4[q] = (float)Ab[q];
        }
        int nrow = n0 + lr;
        if (nrow < N) {
            float4 v = *(const float4*)(W + (size_t)nrow * K + k0 + lc * 4);
            w4[0] = v.x; w4[1] = v.y; w4[2] = v.z; w4[3] = v.w;
        } else { w4[0] = w4[1] = w4[2] = w4[3] = 0.f; }
        __syncthreads();
        #pragma unroll
        for (int q = 0; q < 4; ++q) {
            As[lc * 4 + q][lr] = a4[q];
            Ws[lc * 4 + q][lr] = w4[q];
        }
        __syncthreads();
        #pragma unroll
        for (int kk = 0; kk < 16; ++kk) {
            float4 a = *(const float4*)&As[kk][ty * 4];
            float4 w = *(const float4*)&Ws[kk][tx * 4];
            float av[4] = {a.x, a.y, a.z, a.w};
            float wv[4] = {w.x, w.y, w.z, w.w};
            #pragma unroll
            for (int i = 0; i < 4; ++i)
                #pragma unroll
                for (int j = 0; j < 4; ++j)
                    acc[i][j] += av[i] * wv[j];
        }
    }
    #pragma unroll
    for (int i = 0; i < 4; ++i) {
        int row = m0 + ty * 4 + i;
        #pragma unroll
        for (int j = 0; j < 4; ++j) {
            int col = n0 + tx * 4 + j;
            if (col < N) {
                float v = acc[i][j] + bias[col];
                if (OUTT == 1) ((_Float16*)Cptr)[(size_t)row * N + col] = (_Float16)v;
                else           ((float*)Cptr)[(size_t)row * N + col] = v;
            }
        }
    }
}

// ---------------- 4-batch zero-exchange LSTM, 1024 threads (k-quarter split) ----------------
// 32 blocks x 1024 threads. thread = (q = tid>>8 in 0..3, j = tid&255).
// Matvec: thread (q,j) computes partials of gate rows {g*256+j} over k in
// [q*64, q*64+64) for all 4 batches from packed W (coalesced 64B chunks).
// Update: thread == unit (b = tid>>8, j): sums 4 q-partials, applies gates.
// 16 waves/block -> 4 waves/SIMD (vs 2 before) to hide L2 latency.
// OUTT: 0 = f32, 1 = f16
template<int OUTT>
__global__ __launch_bounds__(1024)
void lstm_nb4q(const float* __restrict__ xg,      // [M][1024] phased
               const float* __restrict__ Pf, const float* __restrict__ Pb, // packed Whh
               const unsigned* __restrict__ len_u32,
               const unsigned* __restrict__ dflags,
               float* __restrict__ Hsav,          // [2][Bq][Hq]
               float* __restrict__ Csav,          // [2][Bq][Hq]
               void* __restrict__ out,            // [M][512]
               int t0, int t1)
{
    __shared__ float hsh[4][256];
    __shared__ float scr[4][4][4][256];   // [q][b][g][j]

    const int tid = threadIdx.x;
    const int bid = blockIdx.x;
    const int dir = bid >> 4;
    const int b0  = (bid & 15) * 4;
    const int j   = tid & 255;
    const int q   = tid >> 8;            // k-quarter for matvec; batch index for update
    const float* __restrict__ P = dir ? Pb : Pf;
    const bool l64 = (dflags[0] & 2u) != 0u;

    // update unit: (bu = q, j)
    const int bu = q;
    const int mylen = (int)(l64 ? len_u32[2 * (b0 + bu)] : len_u32[b0 + bu]);

    float c = 0.f;
    if (t0 == 0) {
        hsh[bu][j] = 0.f;
    } else {
        c = Csav[((size_t)dir * Bq + b0 + bu) * Hq + j];
        hsh[bu][j] = Hsav[((size_t)dir * Bq + b0 + bu) * Hq + j];
    }
    __syncthreads();

    for (int t = t0; t < t1; ++t) {
        const int teff = dir ? (Tq - 1 - t) : t;
        // prefetch xg for this thread's update unit (consumed after matvec)
        const float* xr = xg + ((size_t)(b0 + bu) * Tq + teff) * 1024 + j;
        float xv0 = xr[0], xv1 = xr[256], xv2 = xr[512], xv3 = xr[768];

        // matvec partials: 4 gate rows x 4 batches over k in [q*64, q*64+64)
        float a[4][4] = {};   // [g][b]
        const float* Pq = P + ((size_t)(q * 16) * 256 + j) * 16;
        #pragma unroll 4
        for (int kq = 0; kq < 16; ++kq) {
            const float4* p = (const float4*)(Pq + (size_t)kq * 256 * 16);
            float4 w0 = p[0], w1 = p[1], w2 = p[2], w3 = p[3];
            #pragma unroll
            for (int b = 0; b < 4; ++b) {
                float4 hv = *(const float4*)(&hsh[b][q * 64 + kq * 4]);
                a[0][b] += w0.x * hv.x + w0.y * hv.y + w0.z * hv.z + w0.w * hv.w;
                a[1][b] += w1.x * hv.x + w1.y * hv.y + w1.z * hv.z + w1.w * hv.w;
                a[2][b] += w2.x * hv.x + w2.y * hv.y + w2.z * hv.z + w2.w * hv.w;
                a[3][b] += w3.x * hv.x + w3.y * hv.y + w3.z * hv.z + w3.w * hv.w;
            }
        }
        #pragma unroll
        for (int b = 0; b < 4; ++b)
            #pragma unroll
            for (int g = 0; g < 4; ++g)
                scr[q][b][g][j] = a[g][b];
        __syncthreads();

        // update: thread (bu, j)
        {
            float g0 = xv0 + scr[0][bu][0][j] + scr[1][bu][0][j] + scr[2][bu][0][j] + scr[3][bu][0][j];
            float g1 = xv1 + scr[0][bu][1][j] + scr[1][bu][1][j] + scr[2][bu][1][j] + scr[3][bu][1][j];
            float g2 = xv2 + scr[0][bu][2][j] + scr[1][bu][2][j] + scr[2][bu][2][j] + scr[3][bu][2][j];
            float g3 = xv3 + scr[0][bu][3][j] + scr[1][bu][3][j] + scr[2][bu][3][j] + scr[3][bu][3][j];
            float ig = sigmoidf_(g0), fg = sigmoidf_(g1);
            float gg = tanhf_(g2), og = sigmoidf_(g3);
            float cn = fg * c + ig * gg;
            float hn = og * tanhf_(cn);
            bool m = (teff < mylen);
            float hold = hsh[bu][j];
            float hm = m ? hn : hold;
            c = m ? cn : c;
            hsh[bu][j] = hm;
            size_t orow = (size_t)(b0 + bu) * Tq + teff;
            if (OUTT == 1) ((_Float16*)out)[orow * 512 + dir * 256 + j] = (_Float16)hm;
            else           ((float*)out)[orow * 512 + dir * 256 + j] = hm;
        }
        __syncthreads();
    }
    Csav[((size_t)dir * Bq + b0 + bu) * Hq + j] = c;
    Hsav[((size_t)dir * Bq + b0 + bu) * Hq + j] = hsh[bu][j];
}

extern "C" void kernel_launch(void* const* d_in, const int* in_sizes, int n_in,
                              void* d_out, int out_size, void* d_ws, size_t ws_size,
                              hipStream_t stream)
{
    const unsigned* words  = (const unsigned*)d_in[0];
    const unsigned* lens   = (const unsigned*)d_in[1];
    const float* emb     = (const float*)d_in[2];
    const float* l1f_Wih = (const float*)d_in[3];
    const float* l1f_Whh = (const float*)d_in[4];
    const float* l1f_bih = (const float*)d_in[5];
    const float* l1f_bhh = (const float*)d_in[6];
    const float* l1b_Wih = (const float*)d_in[7];
    const float* l1b_Whh = (const float*)d_in[8];
    const float* l1b_bih = (const float*)d_in[9];
    const float* l1b_bhh = (const float*)d_in[10];
    const float* l2f_Wih = (const float*)d_in[11];
    const float* l2f_Whh = (const float*)d_in[12];
    const float* l2f_bih = (const float*)d_in[13];
    const float* l2f_bhh = (const float*)d_in[14];
    const float* l2b_Wih = (const float*)d_in[15];
    const float* l2b_Whh = (const float*)d_in[16];
    const float* l2b_bih = (const float*)d_in[17];
    const float* l2b_bhh = (const float*)d_in[18];
    const float* cls_W   = (const float*)d_in[19];
    const float* cls_b   = (const float*)d_in[20];
    (void)in_sizes; (void)n_in; (void)out_size; (void)ws_size;

    char* ws = (char*)d_ws;
    size_t off = 0;
    auto alloc = [&](size_t b) { void* p = ws + off; off += (b + 255) & ~(size_t)255; return p; };
    float*     xg = (float*)alloc((size_t)Mq * 1024 * 4);   // 128 MiB, reused 4x
    float*     o1 = (float*)alloc((size_t)Mq * 512 * 4);    // 64 MiB
    _Float16*  o2 = (_Float16*)alloc((size_t)Mq * 512 * 2); // 32 MiB
    float*   Wpk = (float*)alloc((size_t)4 * 1024 * 256 * 4); // 4 MiB packed Whh
    float*   Hsav = (float*)alloc((size_t)2 * Bq * Hq * 4);
    float*   Csav = (float*)alloc((size_t)2 * Bq * Hq * 4);
    float* biasbuf = (float*)alloc((size_t)4 * 1024 * 4);
    unsigned* dflags = (unsigned*)alloc(256);

    const float* b1f = biasbuf, *b1b = biasbuf + 1024, *b2f = biasbuf + 2048, *b2b = biasbuf + 3072;
    float* P1f = Wpk, *P1b = Wpk + 262144, *P2f = Wpk + 2 * 262144, *P2b = Wpk + 3 * 262144;

    detect_int64<<<1, 256, 0, stream>>>(words, lens, dflags);
    bias_kernel<<<dim3(16), 256, 0, stream>>>(l1f_bih, l1f_bhh, l1b_bih, l1b_bhh,
                                              l2f_bih, l2f_bhh, l2b_bih, l2b_bhh, biasbuf);
    pack_whh<<<dim3(256), 256, 0, stream>>>(l1f_Whh, P1f);
    pack_whh<<<dim3(256), 256, 0, stream>>>(l1b_Whh, P1b);
    pack_whh<<<dim3(256), 256, 0, stream>>>(l2f_Whh, P2f);
    pack_whh<<<dim3(256), 256, 0, stream>>>(l2b_Whh, P2b);

    dim3 ggrid(1024 / 64, Mq / 64);
    // ---- layer 1 ----
    gemm_kernel<2, 0><<<ggrid, 256, 0, stream>>>(nullptr, words, emb, dflags,
        l1f_Wih, l1b_Wih, b1f, b1b, xg, Mq, 1024, Eq);
    lstm_nb4q<0><<<32, 1024, 0, stream>>>(xg, P1f, P1b, lens, dflags, Hsav, Csav, o1, 0, 256);
    gemm_kernel<2, 0><<<ggrid, 256, 0, stream>>>(nullptr, words, emb, dflags,
        l1b_Wih, l1f_Wih, b1b, b1f, xg, Mq, 1024, Eq);
    lstm_nb4q<0><<<32, 1024, 0, stream>>>(xg, P1f, P1b, lens, dflags, Hsav, Csav, o1, 256, 512);
    // ---- layer 2 ----
    gemm_kernel<0, 0><<<ggrid, 256, 0, stream>>>(o1, nullptr, nullptr, dflags,
        l2f_Wih, l2b_Wih, b2f, b2b, xg, Mq, 1024, 512);
    lstm_nb4q<1><<<32, 1024, 0, stream>>>(xg, P2f, P2b, lens, dflags, Hsav, Csav, o2, 0, 256);
    gemm_kernel<0, 0><<<ggrid, 256, 0, stream>>>(o1, nullptr, nullptr, dflags,
        l2b_Wih, l2f_Wih, b2b, b2f, xg, Mq, 1024, 512);
    lstm_nb4q<1><<<32, 1024, 0, stream>>>(xg, P2f, P2b, lens, dflags, Hsav, Csav, o2, 256, 512);
    // ---- classifier -> d_out (f32) ----
    gemm_kernel<3, 0><<<dim3(1, Mq / 64), 256, 0, stream>>>(o2, nullptr, nullptr, dflags,
        cls_W, cls_W, cls_b, cls_b, d_out, Mq, NTAGS, 512);
}

// Round 13
// 9665.662 us; speedup vs baseline: 1.7643x; 1.7643x over previous
//
#include <hip/hip_runtime.h>
#include <hip/hip_bf16.h>

#define Bq 64
#define Tq 512
#define Eq 128
#define Hq 256
#define NTAGS 50
#define Mq (Bq*Tq)   // 32768

typedef _Float16 half2_t __attribute__((ext_vector_type(2)));

__device__ __forceinline__ float sigmoidf_(float x) { return 1.f / (1.f + __expf(-x)); }
__device__ __forceinline__ float tanhf_(float x) {
    float e = __expf(2.f * x);
    return 1.f - 2.f / (e + 1.f);
}

#if __has_builtin(__builtin_amdgcn_fdot2)
__device__ __forceinline__ float dot2_(unsigned w, unsigned h, float acc) {
    return __builtin_amdgcn_fdot2(__builtin_bit_cast(half2_t, w),
                                  __builtin_bit_cast(half2_t, h), acc, false);
}
#else
__device__ __forceinline__ float dot2_(unsigned w, unsigned h, float acc) {
    half2_t wv = __builtin_bit_cast(half2_t, w);
    half2_t hv = __builtin_bit_cast(half2_t, h);
    return acc + (float)wv.x * (float)hv.x + (float)wv.y * (float)hv.y;
}
#endif

// ---------------- dtype detection: int32 vs int64 for words/lengths ----------------
__global__ void detect_int64(const unsigned* __restrict__ words,
                             const unsigned* __restrict__ lens,
                             unsigned* __restrict__ dflags) {
    __shared__ int wbad, lbad, wnz, lnz;
    if (threadIdx.x == 0) { wbad = 0; lbad = 0; wnz = 0; lnz = 0; }
    __syncthreads();
    for (int i = threadIdx.x; i < 16384; i += blockDim.x) {
        if (words[2 * i + 1] != 0u) wbad = 1;
        if (words[2 * i] != 0u) wnz = 1;
    }
    for (int i = threadIdx.x; i < 32; i += blockDim.x) {
        if (lens[2 * i + 1] != 0u) lbad = 1;
        if (lens[2 * i] != 0u) lnz = 1;
    }
    __syncthreads();
    if (threadIdx.x == 0) {
        unsigned f = 0;
        if (!wbad && wnz) f |= 1u;
        if (!lbad && lnz) f |= 2u;
        dflags[0] = f;
    }
}

// ---------------- bias: bias[l][d][n] = bih + bhh ----------------
__global__ void bias_kernel(const float* b1f_ih, const float* b1f_hh,
                            const float* b1b_ih, const float* b1b_hh,
                            const float* b2f_ih, const float* b2f_hh,
                            const float* b2b_ih, const float* b2b_hh,
                            float* bias) {   // [4][1024]: l1f,l1b,l2f,l2b
    int i = blockIdx.x * blockDim.x + threadIdx.x;
    if (i >= 4096) return;
    int l = i >> 11, d = (i >> 10) & 1, nn = i & 1023;
    float v;
    if (l == 0) v = d ? (b1b_ih[nn] + b1b_hh[nn]) : (b1f_ih[nn] + b1f_hh[nn]);
    else        v = d ? (b2b_ih[nn] + b2b_hh[nn]) : (b2f_ih[nn] + b2f_hh[nn]);
    bias[i] = v;
}

// ---------------- Whh f16 packing: W[1024][256] -> P16[((k4*256)+j)*16 + g*4 + kk] ----------------
// Chunk per (k4,j) = 32B: g-major, k-minor (4 halves per gate).
__global__ void pack_whh16(const float* __restrict__ W, unsigned short* __restrict__ P) {
    int t = blockIdx.x * 256 + threadIdx.x;   // 0..65535
    if (t >= 65536) return;
    int g = t & 3, j = (t >> 2) & 255, k4 = t >> 10;   // k4: 0..63
    int row = g * 256 + j;
    float4 v = *(const float4*)(W + (size_t)row * 256 + k4 * 4);
    _Float16 h4[4] = {(_Float16)v.x, (_Float16)v.y, (_Float16)v.z, (_Float16)v.w};
    *(unsigned long long*)(P + ((size_t)(k4 * 256 + j) * 16 + g * 4)) =
        *(const unsigned long long*)h4;
}

// ---------------- f32 GEMM: C[M,N] = A[M,K] @ W[N,K]^T + bias (unchanged, passing) ----------------
// AMODE: 0 = A f32, 2 = A gathered from emb via words (dtype-adaptive), 3 = A f16
// OUTT:  0 = f32, 1 = f16
template<int AMODE, int OUTT>
__global__ __launch_bounds__(256)
void gemm_kernel(const void* __restrict__ Aptr, const unsigned* __restrict__ words_u32,
                 const float* __restrict__ emb, const unsigned* __restrict__ dflags,
                 const float* __restrict__ Wlo, const float* __restrict__ Whi,
                 const float* __restrict__ blo, const float* __restrict__ bhi,
                 void* __restrict__ Cptr, int M, int N, int K)
{
    __shared__ float As[16][68];
    __shared__ float Ws[16][68];
    const int tx = threadIdx.x & 15, ty = threadIdx.x >> 4;
    const int m0 = blockIdx.y * 64, n0 = blockIdx.x * 64;
    const bool hi = ((m0 & 511) >= 256);
    const float* W = hi ? Whi : Wlo;
    const float* bias = hi ? bhi : blo;
    const int lr = threadIdx.x >> 2, lc = threadIdx.x & 3;
    bool w64 = false;
    if (AMODE == 2) w64 = (dflags[0] & 1u) != 0u;
    float acc[4][4] = {};
    for (int k0 = 0; k0 < K; k0 += 16) {
        float a4[4], w4[4];
        if (AMODE == 2) {
            int m = m0 + lr;
            int w = (int)(w64 ? words_u32[2 * m] : words_u32[m]);
            float4 v = *(const float4*)(emb + (size_t)w * Eq + k0 + lc * 4);
            a4[0] = v.x; a4[1] = v.y; a4[2] = v.z; a4[3] = v.w;
        } else if (AMODE == 0) {
            float4 v = *(const float4*)((const float*)Aptr + (size_t)(m0 + lr) * K + k0 + lc * 4);
            a4[0] = v.x; a4[1] = v.y; a4[2] = v.z; a4[3] = v.w;
        } else {
            const _Float16* Ab = (const _Float16*)Aptr + (size_t)(m0 + lr) * K + k0 + lc * 4;
            #pragma unroll
            for (int q = 0; q < 4; ++q) a4[q] = (float)Ab[q];
        }
        int nrow = n0 + lr;
        if (nrow < N) {
            float4 v = *(const float4*)(W + (size_t)nrow * K + k0 + lc * 4);
            w4[0] = v.x; w4[1] = v.y; w4[2] = v.z; w4[3] = v.w;
        } else { w4[0] = w4[1] = w4[2] = w4[3] = 0.f; }
        __syncthreads();
        #pragma unroll
        for (int q = 0; q < 4; ++q) {
            As[lc * 4 + q][lr] = a4[q];
            Ws[lc * 4 + q][lr] = w4[q];
        }
        __syncthreads();
        #pragma unroll
        for (int kk = 0; kk < 16; ++kk) {
            float4 a = *(const float4*)&As[kk][ty * 4];
            float4 w = *(const float4*)&Ws[kk][tx * 4];
            float av[4] = {a.x, a.y, a.z, a.w};
            float wv[4] = {w.x, w.y, w.z, w.w};
            #pragma unroll
            for (int i = 0; i < 4; ++i)
                #pragma unroll
                for (int j = 0; j < 4; ++j)
                    acc[i][j] += av[i] * wv[j];
        }
    }
    #pragma unroll
    for (int i = 0; i < 4; ++i) {
        int row = m0 + ty * 4 + i;
        #pragma unroll
        for (int j = 0; j < 4; ++j) {
            int col = n0 + tx * 4 + j;
            if (col < N) {
                float v = acc[i][j] + bias[col];
                if (OUTT == 1) ((_Float16*)Cptr)[(size_t)row * N + col] = (_Float16)v;
                else           ((float*)Cptr)[(size_t)row * N + col] = v;
            }
        }
    }
}

// ---------------- 4-batch zero-exchange LSTM, f16 W + fdot2 ----------------
// 32 blocks x 1024 threads. thread = (q = tid>>8, j = tid&255).
// Matvec: thread (q,j) computes partials of gate rows {g*256+j} over k in
// [q*64, q*64+64) for all 4 batches from f16-packed W (32B chunk per (k4,j)).
// h carried in f32 LDS (masking exact) + mirrored f16 for the dot.
// Update: thread == unit (b = tid>>8, j). OUTT: 0 = f32, 1 = f16
template<int OUTT>
__global__ __launch_bounds__(1024)
void lstm_f16w(const float* __restrict__ xg,      // [M][1024] phased
               const unsigned short* __restrict__ Pf, const unsigned short* __restrict__ Pb,
               const unsigned* __restrict__ len_u32,
               const unsigned* __restrict__ dflags,
               float* __restrict__ Hsav,          // [2][Bq][Hq]
               float* __restrict__ Csav,          // [2][Bq][Hq]
               void* __restrict__ out,            // [M][512]
               int t0, int t1)
{
    __shared__ float hsh[4][256];
    __shared__ unsigned short hsh16[4][256];
    __shared__ float scr[4][4][4][256];   // [q][b][g][j]

    const int tid = threadIdx.x;
    const int bid = blockIdx.x;
    const int dir = bid >> 4;
    const int b0  = (bid & 15) * 4;
    const int j   = tid & 255;
    const int q   = tid >> 8;            // k-quarter for matvec; batch index for update
    const unsigned short* __restrict__ P = dir ? Pb : Pf;
    const bool l64 = (dflags[0] & 2u) != 0u;

    const int bu = q;
    const int mylen = (int)(l64 ? len_u32[2 * (b0 + bu)] : len_u32[b0 + bu]);

    float c = 0.f;
    {
        float h0;
        if (t0 == 0) {
            h0 = 0.f;
        } else {
            c  = Csav[((size_t)dir * Bq + b0 + bu) * Hq + j];
            h0 = Hsav[((size_t)dir * Bq + b0 + bu) * Hq + j];
        }
        hsh[bu][j] = h0;
        _Float16 hh = (_Float16)h0;
        hsh16[bu][j] = __builtin_bit_cast(unsigned short, hh);
    }
    __syncthreads();

    for (int t = t0; t < t1; ++t) {
        const int teff = dir ? (Tq - 1 - t) : t;
        // prefetch xg for this thread's update unit (consumed after matvec)
        const float* xr = xg + ((size_t)(b0 + bu) * Tq + teff) * 1024 + j;
        float xv0 = xr[0], xv1 = xr[256], xv2 = xr[512], xv3 = xr[768];

        // matvec partials: 4 gate rows x 4 batches over k in [q*64, q*64+64)
        float a[4][4] = {};   // [g][b]
        #pragma unroll 4
        for (int kq = 0; kq < 16; ++kq) {
            const uint4* pc = (const uint4*)(P + ((size_t)((q * 16 + kq) * 256 + j) * 16));
            uint4 w01 = pc[0];   // g0:{k0k1},{k2k3}, g1:{k0k1},{k2k3}
            uint4 w23 = pc[1];   // g2, g3
            #pragma unroll
            for (int b = 0; b < 4; ++b) {
                uint2 hv = *(const uint2*)(&hsh16[b][q * 64 + kq * 4]);
                a[0][b] = dot2_(w01.x, hv.x, a[0][b]);
                a[0][b] = dot2_(w01.y, hv.y, a[0][b]);
                a[1][b] = dot2_(w01.z, hv.x, a[1][b]);
                a[1][b] = dot2_(w01.w, hv.y, a[1][b]);
                a[2][b] = dot2_(w23.x, hv.x, a[2][b]);
                a[2][b] = dot2_(w23.y, hv.y, a[2][b]);
                a[3][b] = dot2_(w23.z, hv.x, a[3][b]);
                a[3][b] = dot2_(w23.w, hv.y, a[3][b]);
            }
        }
        #pragma unroll
        for (int b = 0; b < 4; ++b)
            #pragma unroll
            for (int g = 0; g < 4; ++g)
                scr[q][b][g][j] = a[g][b];
        __syncthreads();

        // update: thread (bu, j)
        {
            float g0 = xv0 + scr[0][bu][0][j] + scr[1][bu][0][j] + scr[2][bu][0][j] + scr[3][bu][0][j];
            float g1 = xv1 + scr[0][bu][1][j] + scr[1][bu][1][j] + scr[2][bu][1][j] + scr[3][bu][1][j];
            float g2 = xv2 + scr[0][bu][2][j] + scr[1][bu][2][j] + scr[2][bu][2][j] + scr[3][bu][2][j];
            float g3 = xv3 + scr[0][bu][3][j] + scr[1][bu][3][j] + scr[2][bu][3][j] + scr[3][bu][3][j];
            float ig = sigmoidf_(g0), fg = sigmoidf_(g1);
            float gg = tanhf_(g2), og = sigmoidf_(g3);
            float cn = fg * c + ig * gg;
            float hn = og * tanhf_(cn);
            bool m = (teff < mylen);
            float hold = hsh[bu][j];
            float hm = m ? hn : hold;
            c = m ? cn : c;
            hsh[bu][j] = hm;
            _Float16 hh = (_Float16)hm;
            hsh16[bu][j] = __builtin_bit_cast(unsigned short, hh);
            size_t orow = (size_t)(b0 + bu) * Tq + teff;
            if (OUTT == 1) ((_Float16*)out)[orow * 512 + dir * 256 + j] = (_Float16)hm;
            else           ((float*)out)[orow * 512 + dir * 256 + j] = hm;
        }
        __syncthreads();
    }
    Csav[((size_t)dir * Bq + b0 + bu) * Hq + j] = c;
    Hsav[((size_t)dir * Bq + b0 + bu) * Hq + j] = hsh[bu][j];
}

extern "C" void kernel_launch(void* const* d_in, const int* in_sizes, int n_in,
                              void* d_out, int out_size, void* d_ws, size_t ws_size,
                              hipStream_t stream)
{
    const unsigned* words  = (const unsigned*)d_in[0];
    const unsigned* lens   = (const unsigned*)d_in[1];
    const float* emb     = (const float*)d_in[2];
    const float* l1f_Wih = (const float*)d_in[3];
    const float* l1f_Whh = (const float*)d_in[4];
    const float* l1f_bih = (const float*)d_in[5];
    const float* l1f_bhh = (const float*)d_in[6];
    const float* l1b_Wih = (const float*)d_in[7];
    const float* l1b_Whh = (const float*)d_in[8];
    const float* l1b_bih = (const float*)d_in[9];
    const float* l1b_bhh = (const float*)d_in[10];
    const float* l2f_Wih = (const float*)d_in[11];
    const float* l2f_Whh = (const float*)d_in[12];
    const float* l2f_bih = (const float*)d_in[13];
    const float* l2f_bhh = (const float*)d_in[14];
    const float* l2b_Wih = (const float*)d_in[15];
    const float* l2b_Whh = (const float*)d_in[16];
    const float* l2b_bih = (const float*)d_in[17];
    const float* l2b_bhh = (const float*)d_in[18];
    const float* cls_W   = (const float*)d_in[19];
    const float* cls_b   = (const float*)d_in[20];
    (void)in_sizes; (void)n_in; (void)out_size; (void)ws_size;

    char* ws = (char*)d_ws;
    size_t off = 0;
    auto alloc = [&](size_t b) { void* p = ws + off; off += (b + 255) & ~(size_t)255; return p; };
    float*     xg = (float*)alloc((size_t)Mq * 1024 * 4);   // 128 MiB, reused 4x
    float*     o1 = (float*)alloc((size_t)Mq * 512 * 4);    // 64 MiB
    _Float16*  o2 = (_Float16*)alloc((size_t)Mq * 512 * 2); // 32 MiB
    unsigned short* Wpk = (unsigned short*)alloc((size_t)4 * 1024 * 256 * 2); // 2 MiB f16 packed
    float*   Hsav = (float*)alloc((size_t)2 * Bq * Hq * 4);
    float*   Csav = (float*)alloc((size_t)2 * Bq * Hq * 4);
    float* biasbuf = (float*)alloc((size_t)4 * 1024 * 4);
    unsigned* dflags = (unsigned*)alloc(256);

    const float* b1f = biasbuf, *b1b = biasbuf + 1024, *b2f = biasbuf + 2048, *b2b = biasbuf + 3072;
    unsigned short* P1f = Wpk, *P1b = Wpk + 262144, *P2f = Wpk + 2 * 262144, *P2b = Wpk + 3 * 262144;

    detect_int64<<<1, 256, 0, stream>>>(words, lens, dflags);
    bias_kernel<<<dim3(16), 256, 0, stream>>>(l1f_bih, l1f_bhh, l1b_bih, l1b_bhh,
                                              l2f_bih, l2f_bhh, l2b_bih, l2b_bhh, biasbuf);
    pack_whh16<<<dim3(256), 256, 0, stream>>>(l1f_Whh, P1f);
    pack_whh16<<<dim3(256), 256, 0, stream>>>(l1b_Whh, P1b);
    pack_whh16<<<dim3(256), 256, 0, stream>>>(l2f_Whh, P2f);
    pack_whh16<<<dim3(256), 256, 0, stream>>>(l2b_Whh, P2b);

    dim3 ggrid(1024 / 64, Mq / 64);
    // ---- layer 1 ----
    gemm_kernel<2, 0><<<ggrid, 256, 0, stream>>>(nullptr, words, emb, dflags,
        l1f_Wih, l1b_Wih, b1f, b1b, xg, Mq, 1024, Eq);
    lstm_f16w<0><<<32, 1024, 0, stream>>>(xg, P1f, P1b, lens, dflags, Hsav, Csav, o1, 0, 256);
    gemm_kernel<2, 0><<<ggrid, 256, 0, stream>>>(nullptr, words, emb, dflags,
        l1b_Wih, l1f_Wih, b1b, b1f, xg, Mq, 1024, Eq);
    lstm_f16w<0><<<32, 1024, 0, stream>>>(xg, P1f, P1b, lens, dflags, Hsav, Csav, o1, 256, 512);
    // ---- layer 2 ----
    gemm_kernel<0, 0><<<ggrid, 256, 0, stream>>>(o1, nullptr, nullptr, dflags,
        l2f_Wih, l2b_Wih, b2f, b2b, xg, Mq, 1024, 512);
    lstm_f16w<1><<<32, 1024, 0, stream>>>(xg, P2f, P2b, lens, dflags, Hsav, Csav, o2, 0, 256);
    gemm_kernel<0, 0><<<ggrid, 256, 0, stream>>>(o1, nullptr, nullptr, dflags,
        l2b_Wih, l2f_Wih, b2b, b2f, xg, Mq, 1024, 512);
    lstm_f16w<1><<<32, 1024, 0, stream>>>(xg, P2f, P2b, lens, dflags, Hsav, Csav, o2, 256, 512);
    // ---- classifier -> d_out (f32) ----
    gemm_kernel<3, 0><<<dim3(1, Mq / 64), 256, 0, stream>>>(o2, nullptr, nullptr, dflags,
        cls_W, cls_W, cls_b, cls_b, d_out, Mq, NTAGS, 512);
}

// Round 14
// 7342.398 us; speedup vs baseline: 2.3226x; 1.3164x over previous
//
#include <hip/hip_runtime.h>
#include <hip/hip_bf16.h>

#define Bq 64
#define Tq 512
#define Eq 128
#define Hq 256
#define NTAGS 50
#define Mq (Bq*Tq)   // 32768

typedef _Float16 half2_t __attribute__((ext_vector_type(2)));

__device__ __forceinline__ float sigmoidf_(float x) { return 1.f / (1.f + __expf(-x)); }
__device__ __forceinline__ float tanhf_(float x) {
    float e = __expf(2.f * x);
    return 1.f - 2.f / (e + 1.f);
}

#if __has_builtin(__builtin_amdgcn_fdot2)
__device__ __forceinline__ float dot2_(unsigned w, unsigned h, float acc) {
    return __builtin_amdgcn_fdot2(__builtin_bit_cast(half2_t, w),
                                  __builtin_bit_cast(half2_t, h), acc, false);
}
#else
__device__ __forceinline__ float dot2_(unsigned w, unsigned h, float acc) {
    half2_t wv = __builtin_bit_cast(half2_t, w);
    half2_t hv = __builtin_bit_cast(half2_t, h);
    return acc + (float)wv.x * (float)hv.x + (float)wv.y * (float)hv.y;
}
#endif

// ---------------- dtype detection: int32 vs int64 for words/lengths ----------------
__global__ void detect_int64(const unsigned* __restrict__ words,
                             const unsigned* __restrict__ lens,
                             unsigned* __restrict__ dflags) {
    __shared__ int wbad, lbad, wnz, lnz;
    if (threadIdx.x == 0) { wbad = 0; lbad = 0; wnz = 0; lnz = 0; }
    __syncthreads();
    for (int i = threadIdx.x; i < 16384; i += blockDim.x) {
        if (words[2 * i + 1] != 0u) wbad = 1;
        if (words[2 * i] != 0u) wnz = 1;
    }
    for (int i = threadIdx.x; i < 32; i += blockDim.x) {
        if (lens[2 * i + 1] != 0u) lbad = 1;
        if (lens[2 * i] != 0u) lnz = 1;
    }
    __syncthreads();
    if (threadIdx.x == 0) {
        unsigned f = 0;
        if (!wbad && wnz) f |= 1u;
        if (!lbad && lnz) f |= 2u;
        dflags[0] = f;
    }
}

// ---------------- bias: bias[l][d][n] = bih + bhh ----------------
__global__ void bias_kernel(const float* b1f_ih, const float* b1f_hh,
                            const float* b1b_ih, const float* b1b_hh,
                            const float* b2f_ih, const float* b2f_hh,
                            const float* b2b_ih, const float* b2b_hh,
                            float* bias) {   // [4][1024]: l1f,l1b,l2f,l2b
    int i = blockIdx.x * blockDim.x + threadIdx.x;
    if (i >= 4096) return;
    int l = i >> 11, d = (i >> 10) & 1, nn = i & 1023;
    float v;
    if (l == 0) v = d ? (b1b_ih[nn] + b1b_hh[nn]) : (b1f_ih[nn] + b1f_hh[nn]);
    else        v = d ? (b2b_ih[nn] + b2b_hh[nn]) : (b2f_ih[nn] + b2f_hh[nn]);
    bias[i] = v;
}

// ---------------- Whh f16 two-plane packing ----------------
// plane_if[(k4*256+j)*8 + g01*4 + kk] : gates 0,1 ; plane_go : gates 2,3.
// Each (k4,j) chunk is 16B per plane -> wave loads are 1KB contiguous.
__global__ void pack_whh16(const float* __restrict__ W,
                           unsigned short* __restrict__ Pif,
                           unsigned short* __restrict__ Pgo) {
    int t = blockIdx.x * 256 + threadIdx.x;   // 0..65535
    if (t >= 65536) return;
    int g = t & 3, j = (t >> 2) & 255, k4 = t >> 10;   // k4: 0..63
    int row = g * 256 + j;
    float4 v = *(const float4*)(W + (size_t)row * 256 + k4 * 4);
    _Float16 h4[4] = {(_Float16)v.x, (_Float16)v.y, (_Float16)v.z, (_Float16)v.w};
    unsigned short* dst = (g < 2 ? Pif : Pgo) + ((size_t)(k4 * 256 + j) * 8 + (g & 1) * 4);
    *(unsigned long long*)dst = *(const unsigned long long*)h4;
}

// ---------------- f32 GEMM: C[M,N] = A[M,K] @ W[N,K]^T + bias (unchanged, passing) ----------------
template<int AMODE, int OUTT>
__global__ __launch_bounds__(256)
void gemm_kernel(const void* __restrict__ Aptr, const unsigned* __restrict__ words_u32,
                 const float* __restrict__ emb, const unsigned* __restrict__ dflags,
                 const float* __restrict__ Wlo, const float* __restrict__ Whi,
                 const float* __restrict__ blo, const float* __restrict__ bhi,
                 void* __restrict__ Cptr, int M, int N, int K)
{
    __shared__ float As[16][68];
    __shared__ float Ws[16][68];
    const int tx = threadIdx.x & 15, ty = threadIdx.x >> 4;
    const int m0 = blockIdx.y * 64, n0 = blockIdx.x * 64;
    const bool hi = ((m0 & 511) >= 256);
    const float* W = hi ? Whi : Wlo;
    const float* bias = hi ? bhi : blo;
    const int lr = threadIdx.x >> 2, lc = threadIdx.x & 3;
    bool w64 = false;
    if (AMODE == 2) w64 = (dflags[0] & 1u) != 0u;
    float acc[4][4] = {};
    for (int k0 = 0; k0 < K; k0 += 16) {
        float a4[4], w4[4];
        if (AMODE == 2) {
            int m = m0 + lr;
            int w = (int)(w64 ? words_u32[2 * m] : words_u32[m]);
            float4 v = *(const float4*)(emb + (size_t)w * Eq + k0 + lc * 4);
            a4[0] = v.x; a4[1] = v.y; a4[2] = v.z; a4[3] = v.w;
        } else if (AMODE == 0) {
            float4 v = *(const float4*)((const float*)Aptr + (size_t)(m0 + lr) * K + k0 + lc * 4);
            a4[0] = v.x; a4[1] = v.y; a4[2] = v.z; a4[3] = v.w;
        } else {
            const _Float16* Ab = (const _Float16*)Aptr + (size_t)(m0 + lr) * K + k0 + lc * 4;
            #pragma unroll
            for (int q = 0; q < 4; ++q) a4[q] = (float)Ab[q];
        }
        int nrow = n0 + lr;
        if (nrow < N) {
            float4 v = *(const float4*)(W + (size_t)nrow * K + k0 + lc * 4);
            w4[0] = v.x; w4[1] = v.y; w4[2] = v.z; w4[3] = v.w;
        } else { w4[0] = w4[1] = w4[2] = w4[3] = 0.f; }
        __syncthreads();
        #pragma unroll
        for (int q = 0; q < 4; ++q) {
            As[lc * 4 + q][lr] = a4[q];
            Ws[lc * 4 + q][lr] = w4[q];
        }
        __syncthreads();
        #pragma unroll
        for (int kk = 0; kk < 16; ++kk) {
            float4 a = *(const float4*)&As[kk][ty * 4];
            float4 w = *(const float4*)&Ws[kk][tx * 4];
            float av[4] = {a.x, a.y, a.z, a.w};
            float wv[4] = {w.x, w.y, w.z, w.w};
            #pragma unroll
            for (int i = 0; i < 4; ++i)
                #pragma unroll
                for (int j = 0; j < 4; ++j)
                    acc[i][j] += av[i] * wv[j];
        }
    }
    #pragma unroll
    for (int i = 0; i < 4; ++i) {
        int row = m0 + ty * 4 + i;
        #pragma unroll
        for (int j = 0; j < 4; ++j) {
            int col = n0 + tx * 4 + j;
            if (col < N) {
                float v = acc[i][j] + bias[col];
                if (OUTT == 1) ((_Float16*)Cptr)[(size_t)row * N + col] = (_Float16)v;
                else           ((float*)Cptr)[(size_t)row * N + col] = v;
            }
        }
    }
}

// ---------------- 4-batch zero-exchange LSTM, f16 W: regs(kq0-3) + LDS(kq4-5) + stream(kq6-15) ----------------
// 32 blocks x 1024 threads. thread = (q = tid>>8, j = tid&255).
// Same math/accumulation order as round 13 (bit-identical); only W residency differs.
// OUTT: 0 = f32, 1 = f16
template<int OUTT>
__global__ __launch_bounds__(1024)
void lstm_f16w(const float* __restrict__ xg,      // [M][1024] phased
               const unsigned short* __restrict__ Pfif, const unsigned short* __restrict__ Pfgo,
               const unsigned short* __restrict__ Pbif, const unsigned short* __restrict__ Pbgo,
               const unsigned* __restrict__ len_u32,
               const unsigned* __restrict__ dflags,
               float* __restrict__ Hsav,          // [2][Bq][Hq]
               float* __restrict__ Csav,          // [2][Bq][Hq]
               void* __restrict__ out,            // [M][512]
               int t0, int t1)
{
    extern __shared__ char lds_raw[];
    float* scr = (float*)lds_raw;                                   // [4][4][4][256] 64KB
    unsigned short* wifl = (unsigned short*)(lds_raw + 65536);      // [4][2][256][8]  32KB
    unsigned short* wgol = (unsigned short*)(lds_raw + 65536 + 32768); // 32KB
    float* hsh = (float*)(lds_raw + 131072);                        // [4][256] 4KB
    unsigned short* hsh16 = (unsigned short*)(lds_raw + 135168);    // [4][256] 2KB

    const int tid = threadIdx.x;
    const int bid = blockIdx.x;
    const int dir = bid >> 4;
    const int b0  = (bid & 15) * 4;
    const int j   = tid & 255;
    const int q   = tid >> 8;            // k-quarter for matvec; batch index for update
    const unsigned short* __restrict__ Pif = dir ? Pbif : Pfif;
    const unsigned short* __restrict__ Pgo = dir ? Pbgo : Pfgo;
    const bool l64 = (dflags[0] & 2u) != 0u;

    const int bu = q;
    const int mylen = (int)(l64 ? len_u32[2 * (b0 + bu)] : len_u32[b0 + bu]);

    // stage kq 4..5 into LDS: idx = q*512 + kq2*256 + j  (2048 chunks x 16B per plane)
    for (int idx = tid; idx < 2048; idx += 1024) {
        int jj = idx & 255, kq2 = (idx >> 8) & 1, qq = idx >> 9;
        int gch = qq * 16 + 4 + kq2;
        *(uint4*)(wifl + (size_t)idx * 8) = *(const uint4*)(Pif + ((size_t)gch * 256 + jj) * 8);
        *(uint4*)(wgol + (size_t)idx * 8) = *(const uint4*)(Pgo + ((size_t)gch * 256 + jj) * 8);
    }
    // preload kq 0..3 into registers (live across all steps)
    uint4 wif_r[4], wgo_r[4];
    #pragma unroll
    for (int kq = 0; kq < 4; ++kq) {
        wif_r[kq] = *(const uint4*)(Pif + ((size_t)((q * 16 + kq) * 256 + j)) * 8);
        wgo_r[kq] = *(const uint4*)(Pgo + ((size_t)((q * 16 + kq) * 256 + j)) * 8);
    }

    float c = 0.f;
    {
        float h0;
        if (t0 == 0) {
            h0 = 0.f;
        } else {
            c  = Csav[((size_t)dir * Bq + b0 + bu) * Hq + j];
            h0 = Hsav[((size_t)dir * Bq + b0 + bu) * Hq + j];
        }
        hsh[bu * 256 + j] = h0;
        _Float16 hh = (_Float16)h0;
        hsh16[bu * 256 + j] = __builtin_bit_cast(unsigned short, hh);
    }
    __syncthreads();

    for (int t = t0; t < t1; ++t) {
        const int teff = dir ? (Tq - 1 - t) : t;
        const float* xr = xg + ((size_t)(b0 + bu) * Tq + teff) * 1024 + j;
        float xv0 = xr[0], xv1 = xr[256], xv2 = xr[512], xv3 = xr[768];

        float a[4][4] = {};   // [g][b]
        // kq 0..3 from registers
        #pragma unroll
        for (int kq = 0; kq < 4; ++kq) {
            uint4 wif = wif_r[kq], wgo = wgo_r[kq];
            #pragma unroll
            for (int b = 0; b < 4; ++b) {
                uint2 hv = *(const uint2*)(&hsh16[b * 256 + q * 64 + kq * 4]);
                a[0][b] = dot2_(wif.x, hv.x, a[0][b]);
                a[0][b] = dot2_(wif.y, hv.y, a[0][b]);
                a[1][b] = dot2_(wif.z, hv.x, a[1][b]);
                a[1][b] = dot2_(wif.w, hv.y, a[1][b]);
                a[2][b] = dot2_(wgo.x, hv.x, a[2][b]);
                a[2][b] = dot2_(wgo.y, hv.y, a[2][b]);
                a[3][b] = dot2_(wgo.z, hv.x, a[3][b]);
                a[3][b] = dot2_(wgo.w, hv.y, a[3][b]);
            }
        }
        // kq 4..5 from LDS
        #pragma unroll
        for (int kq2 = 0; kq2 < 2; ++kq2) {
            const int kq = 4 + kq2;
            uint4 wif = *(const uint4*)(wifl + ((size_t)((q * 2 + kq2) * 256 + j)) * 8);
            uint4 wgo = *(const uint4*)(wgol + ((size_t)((q * 2 + kq2) * 256 + j)) * 8);
            #pragma unroll
            for (int b = 0; b < 4; ++b) {
                uint2 hv = *(const uint2*)(&hsh16[b * 256 + q * 64 + kq * 4]);
                a[0][b] = dot2_(wif.x, hv.x, a[0][b]);
                a[0][b] = dot2_(wif.y, hv.y, a[0][b]);
                a[1][b] = dot2_(wif.z, hv.x, a[1][b]);
                a[1][b] = dot2_(wif.w, hv.y, a[1][b]);
                a[2][b] = dot2_(wgo.x, hv.x, a[2][b]);
                a[2][b] = dot2_(wgo.y, hv.y, a[2][b]);
                a[3][b] = dot2_(wgo.z, hv.x, a[3][b]);
                a[3][b] = dot2_(wgo.w, hv.y, a[3][b]);
            }
        }
        // kq 6..15 streamed from global (contiguous 1KB wave loads per plane)
        #pragma unroll 5
        for (int kq = 6; kq < 16; ++kq) {
            uint4 wif = *(const uint4*)(Pif + ((size_t)((q * 16 + kq) * 256 + j)) * 8);
            uint4 wgo = *(const uint4*)(Pgo + ((size_t)((q * 16 + kq) * 256 + j)) * 8);
            #pragma unroll
            for (int b = 0; b < 4; ++b) {
                uint2 hv = *(const uint2*)(&hsh16[b * 256 + q * 64 + kq * 4]);
                a[0][b] = dot2_(wif.x, hv.x, a[0][b]);
                a[0][b] = dot2_(wif.y, hv.y, a[0][b]);
                a[1][b] = dot2_(wif.z, hv.x, a[1][b]);
                a[1][b] = dot2_(wif.w, hv.y, a[1][b]);
                a[2][b] = dot2_(wgo.x, hv.x, a[2][b]);
                a[2][b] = dot2_(wgo.y, hv.y, a[2][b]);
                a[3][b] = dot2_(wgo.z, hv.x, a[3][b]);
                a[3][b] = dot2_(wgo.w, hv.y, a[3][b]);
            }
        }
        #pragma unroll
        for (int b = 0; b < 4; ++b)
            #pragma unroll
            for (int g = 0; g < 4; ++g)
                scr[((q * 4 + b) * 4 + g) * 256 + j] = a[g][b];
        __syncthreads();

        // update: thread (bu, j)
        {
            float g0 = xv0, g1 = xv1, g2 = xv2, g3 = xv3;
            #pragma unroll
            for (int qq = 0; qq < 4; ++qq) {
                g0 += scr[((qq * 4 + bu) * 4 + 0) * 256 + j];
                g1 += scr[((qq * 4 + bu) * 4 + 1) * 256 + j];
                g2 += scr[((qq * 4 + bu) * 4 + 2) * 256 + j];
                g3 += scr[((qq * 4 + bu) * 4 + 3) * 256 + j];
            }
            float ig = sigmoidf_(g0), fg = sigmoidf_(g1);
            float gg = tanhf_(g2), og = sigmoidf_(g3);
            float cn = fg * c + ig * gg;
            float hn = og * tanhf_(cn);
            bool m = (teff < mylen);
            float hold = hsh[bu * 256 + j];
            float hm = m ? hn : hold;
            c = m ? cn : c;
            hsh[bu * 256 + j] = hm;
            _Float16 hh = (_Float16)hm;
            hsh16[bu * 256 + j] = __builtin_bit_cast(unsigned short, hh);
            size_t orow = (size_t)(b0 + bu) * Tq + teff;
            if (OUTT == 1) ((_Float16*)out)[orow * 512 + dir * 256 + j] = (_Float16)hm;
            else           ((float*)out)[orow * 512 + dir * 256 + j] = hm;
        }
        __syncthreads();
    }
    Csav[((size_t)dir * Bq + b0 + bu) * Hq + j] = c;
    Hsav[((size_t)dir * Bq + b0 + bu) * Hq + j] = hsh[bu * 256 + j];
}

extern "C" void kernel_launch(void* const* d_in, const int* in_sizes, int n_in,
                              void* d_out, int out_size, void* d_ws, size_t ws_size,
                              hipStream_t stream)
{
    const unsigned* words  = (const unsigned*)d_in[0];
    const unsigned* lens   = (const unsigned*)d_in[1];
    const float* emb     = (const float*)d_in[2];
    const float* l1f_Wih = (const float*)d_in[3];
    const float* l1f_Whh = (const float*)d_in[4];
    const float* l1f_bih = (const float*)d_in[5];
    const float* l1f_bhh = (const float*)d_in[6];
    const float* l1b_Wih = (const float*)d_in[7];
    const float* l1b_Whh = (const float*)d_in[8];
    const float* l1b_bih = (const float*)d_in[9];
    const float* l1b_bhh = (const float*)d_in[10];
    const float* l2f_Wih = (const float*)d_in[11];
    const float* l2f_Whh = (const float*)d_in[12];
    const float* l2f_bih = (const float*)d_in[13];
    const float* l2f_bhh = (const float*)d_in[14];
    const float* l2b_Wih = (const float*)d_in[15];
    const float* l2b_Whh = (const float*)d_in[16];
    const float* l2b_bih = (const float*)d_in[17];
    const float* l2b_bhh = (const float*)d_in[18];
    const float* cls_W   = (const float*)d_in[19];
    const float* cls_b   = (const float*)d_in[20];
    (void)in_sizes; (void)n_in; (void)out_size; (void)ws_size;

    char* ws = (char*)d_ws;
    size_t off = 0;
    auto alloc = [&](size_t b) { void* p = ws + off; off += (b + 255) & ~(size_t)255; return p; };
    float*     xg = (float*)alloc((size_t)Mq * 1024 * 4);   // 128 MiB, reused 4x
    float*     o1 = (float*)alloc((size_t)Mq * 512 * 4);    // 64 MiB
    _Float16*  o2 = (_Float16*)alloc((size_t)Mq * 512 * 2); // 32 MiB
    unsigned short* Wpk = (unsigned short*)alloc((size_t)8 * 131072 * 2); // 2 MiB: 4 mats x 2 planes
    float*   Hsav = (float*)alloc((size_t)2 * Bq * Hq * 4);
    float*   Csav = (float*)alloc((size_t)2 * Bq * Hq * 4);
    float* biasbuf = (float*)alloc((size_t)4 * 1024 * 4);
    unsigned* dflags = (unsigned*)alloc(256);

    const float* b1f = biasbuf, *b1b = biasbuf + 1024, *b2f = biasbuf + 2048, *b2b = biasbuf + 3072;
    unsigned short* P1fif = Wpk;
    unsigned short* P1fgo = Wpk + 131072;
    unsigned short* P1bif = Wpk + 2 * 131072;
    unsigned short* P1bgo = Wpk + 3 * 131072;
    unsigned short* P2fif = Wpk + 4 * 131072;
    unsigned short* P2fgo = Wpk + 5 * 131072;
    unsigned short* P2bif = Wpk + 6 * 131072;
    unsigned short* P2bgo = Wpk + 7 * 131072;

    const size_t ldsBytes = 65536 + 32768 + 32768 + 4096 + 2048;   // 137216
    hipFuncSetAttribute((const void*)lstm_f16w<0>, hipFuncAttributeMaxDynamicSharedMemorySize, (int)ldsBytes);
    hipFuncSetAttribute((const void*)lstm_f16w<1>, hipFuncAttributeMaxDynamicSharedMemorySize, (int)ldsBytes);

    detect_int64<<<1, 256, 0, stream>>>(words, lens, dflags);
    bias_kernel<<<dim3(16), 256, 0, stream>>>(l1f_bih, l1f_bhh, l1b_bih, l1b_bhh,
                                              l2f_bih, l2f_bhh, l2b_bih, l2b_bhh, biasbuf);
    pack_whh16<<<dim3(256), 256, 0, stream>>>(l1f_Whh, P1fif, P1fgo);
    pack_whh16<<<dim3(256), 256, 0, stream>>>(l1b_Whh, P1bif, P1bgo);
    pack_whh16<<<dim3(256), 256, 0, stream>>>(l2f_Whh, P2fif, P2fgo);
    pack_whh16<<<dim3(256), 256, 0, stream>>>(l2b_Whh, P2bif, P2bgo);

    dim3 ggrid(1024 / 64, Mq / 64);
    // ---- layer 1 ----
    gemm_kernel<2, 0><<<ggrid, 256, 0, stream>>>(nullptr, words, emb, dflags,
        l1f_Wih, l1b_Wih, b1f, b1b, xg, Mq, 1024, Eq);
    lstm_f16w<0><<<32, 1024, ldsBytes, stream>>>(xg, P1fif, P1fgo, P1bif, P1bgo,
        lens, dflags, Hsav, Csav, o1, 0, 256);
    gemm_kernel<2, 0><<<ggrid, 256, 0, stream>>>(nullptr, words, emb, dflags,
        l1b_Wih, l1f_Wih, b1b, b1f, xg, Mq, 1024, Eq);
    lstm_f16w<0><<<32, 1024, ldsBytes, stream>>>(xg, P1fif, P1fgo, P1bif, P1bgo,
        lens, dflags, Hsav, Csav, o1, 256, 512);
    // ---- layer 2 ----
    gemm_kernel<0, 0><<<ggrid, 256, 0, stream>>>(o1, nullptr, nullptr, dflags,
        l2f_Wih, l2b_Wih, b2f, b2b, xg, Mq, 1024, 512);
    lstm_f16w<1><<<32, 1024, ldsBytes, stream>>>(xg, P2fif, P2fgo, P2bif, P2bgo,
        lens, dflags, Hsav, Csav, o2, 0, 256);
    gemm_kernel<0, 0><<<ggrid, 256, 0, stream>>>(o1, nullptr, nullptr, dflags,
        l2b_Wih, l2f_Wih, b2b, b2f, xg, Mq, 1024, 512);
    lstm_f16w<1><<<32, 1024, ldsBytes, stream>>>(xg, P2fif, P2fgo, P2bif, P2bgo,
        lens, dflags, Hsav, Csav, o2, 256, 512);
    // ---- classifier -> d_out (f32) ----
    gemm_kernel<3, 0><<<dim3(1, Mq / 64), 256, 0, stream>>>(o2, nullptr, nullptr, dflags,
        cls_W, cls_W, cls_b, cls_b, d_out, Mq, NTAGS, 512);
}